// Round 1
// baseline (247.604 us; speedup 1.0000x reference)
//
#include <hip/hip_runtime.h>

#define IMG_H 768
#define IMG_W 768
#define N_IMG 32
#define TILE 64
#define HALO 2
#define LW (TILE + 2*HALO)   // 68
#define INV_LOG2 1.44269504088896340736f

__device__ __forceinline__ float fast_sigmoid(float y) {
    return 1.0f / (1.0f + __expf(-y));
}

// Pass 1: compute unnormalized w, accumulate per-image sums.
__global__ __launch_bounds__(256) void wk_pass1(
    const float* __restrict__ y_d, const float* __restrict__ y_gt,
    float* __restrict__ out, float* __restrict__ sums)
{
    __shared__ float pbuf[LW * LW];   // 68*68*4 = 18.5 KB -> 8 blocks/CU

    const int tiles_x = IMG_W / TILE;                    // 12
    const int tiles_per_img = tiles_x * (IMG_H / TILE);  // 144
    int b = blockIdx.x;
    int img = b / tiles_per_img;
    int t = b - img * tiles_per_img;
    int ti = t / tiles_x;
    int tj = t - ti * tiles_x;
    int gi0 = ti * TILE, gj0 = tj * TILE;

    const size_t img_off = (size_t)img * IMG_H * IMG_W;
    const float* __restrict__ yimg = y_d + img_off;
    const float* __restrict__ gimg = y_gt + img_off;
    float* __restrict__ oimg = out + img_off;

    // Stage sigmoid(y) tile + halo into LDS; OOB -> 0 (excluded from S1/S2
    // automatically; valid-neighbor count handled analytically below).
    for (int idx = threadIdx.x; idx < LW * LW; idx += 256) {
        int r = idx / LW;
        int c = idx - r * LW;
        int gi = gi0 - HALO + r;
        int gj = gj0 - HALO + c;
        float p = 0.0f;
        if (gi >= 0 && gi < IMG_H && gj >= 0 && gj < IMG_W)
            p = fast_sigmoid(yimg[gi * IMG_W + gj]);
        pbuf[idx] = p;
    }
    __syncthreads();

    const int j  = threadIdx.x & 63;   // column within tile
    const int rg = threadIdx.x >> 6;   // row group 0..3
    const int r0 = rg * 16;            // this thread's local row start

    const int gj = gj0 + j;
    const int cx = min(gj, HALO) + min(IMG_W - 1 - gj, HALO) + 1;

    // 5-row ring of horizontal window sums (fully unrolled -> static idx)
    float h1[5], h2[5];
#pragma unroll
    for (int k = 0; k < 5; ++k) {
        const float* row = &pbuf[(r0 + k) * LW + j];
        float a0 = row[0], a1 = row[1], a2 = row[2], a3 = row[3], a4 = row[4];
        h1[k] = ((a0 + a1) + (a2 + a3)) + a4;
        h2[k] = ((a0*a0 + a1*a1) + (a2*a2 + a3*a3)) + a4*a4;
    }

    float lsum = 0.0f;
#pragma unroll
    for (int lr = 0; lr < 16; ++lr) {
        const int gi = gi0 + r0 + lr;
        // window sums: all 5 ring slots are exactly the current window rows
        float S1 = ((h1[0] + h1[1]) + (h1[2] + h1[3])) + h1[4];
        float S2 = ((h2[0] + h2[1]) + (h2[2] + h2[3])) + h2[4];
        float pc = pbuf[(r0 + lr + HALO) * LW + (j + HALO)];

        int cy = min(gi, HALO) + min(IMG_H - 1 - gi, HALO) + 1;
        float C = (float)(cy * cx);           // valid window entries incl. center
        float acc = C * pc * pc - 2.0f * pc * S1 + S2;  // center term == 0
        float cons = 1.0f - acc / (C - 1.0f);

        float y  = yimg[gi * IMG_W + gj];     // L1/L2-hot reload of center logit
        float sp = fmaxf(y, 0.0f) + __logf(1.0f + __expf(-fabsf(y)));
        float ent = 1.0f + (pc * y - sp) * INV_LOG2;

        float w = cons * ent;
        w = fmaxf(w, gimg[gi * IMG_W + gj]);
        w = 0.9f * w + 0.1f;
        oimg[gi * IMG_W + gj] = w;
        lsum += w;

        if (lr < 15) {   // slide window: load row r0+lr+5 into leaving slot
            const float* row = &pbuf[(r0 + lr + 5) * LW + j];
            float a0 = row[0], a1 = row[1], a2 = row[2], a3 = row[3], a4 = row[4];
            h1[lr % 5] = ((a0 + a1) + (a2 + a3)) + a4;
            h2[lr % 5] = ((a0*a0 + a1*a1) + (a2*a2 + a3*a3)) + a4*a4;
        }
    }

    // wave reduce + one atomic per wave
#pragma unroll
    for (int off = 32; off > 0; off >>= 1)
        lsum += __shfl_down(lsum, off, 64);
    if (j == 0) atomicAdd(&sums[img], lsum);
}

// Pass 2: divide by per-image mean.
__global__ __launch_bounds__(256) void wk_pass2(
    float* __restrict__ out, const float* __restrict__ sums)
{
    const size_t total4 = (size_t)N_IMG * IMG_H * IMG_W / 4;
    const int per_img4 = IMG_H * IMG_W / 4;   // 147456
    for (size_t i = (size_t)blockIdx.x * blockDim.x + threadIdx.x; i < total4;
         i += (size_t)gridDim.x * blockDim.x) {
        int img = (int)(i / per_img4);
        float scale = (float)(IMG_H * IMG_W) / sums[img];
        float4 v = reinterpret_cast<float4*>(out)[i];
        v.x *= scale; v.y *= scale; v.z *= scale; v.w *= scale;
        reinterpret_cast<float4*>(out)[i] = v;
    }
}

extern "C" void kernel_launch(void* const* d_in, const int* in_sizes, int n_in,
                              void* d_out, int out_size, void* d_ws, size_t ws_size,
                              hipStream_t stream) {
    const float* y_d  = (const float*)d_in[0];
    const float* y_gt = (const float*)d_in[1];
    float* out  = (float*)d_out;
    float* sums = (float*)d_ws;

    hipMemsetAsync(sums, 0, N_IMG * sizeof(float), stream);

    const int tiles_per_img = (IMG_H / TILE) * (IMG_W / TILE);  // 144
    wk_pass1<<<dim3(N_IMG * tiles_per_img), dim3(256), 0, stream>>>(y_d, y_gt, out, sums);
    wk_pass2<<<dim3(2048), dim3(256), 0, stream>>>(out, sums);
}

// Round 3
// 178.790 us; speedup vs baseline: 1.3849x; 1.3849x over previous
//
#include <hip/hip_runtime.h>

#define IMG_H 768
#define IMG_W 768
#define N_IMG 32
#define TILE 64
#define HALO 2
#define LW 68              // 64 + 2*HALO
#define INV_LOG2 1.44269504088896340736f

__device__ __forceinline__ float fast_sigmoid(float y) {
    return 1.0f / (1.0f + __expf(-y));
}

// Horizontal 5-wide window sums (S1=sum p, S2=sum p^2) for 4 output cols,
// from 8 consecutive LDS floats (2x ds_read_b128). Optionally stash the 4
// center p values (cols +2..+5) for a later output row.
#define LOAD_HROW(k, slot, stash)                                              \
    do {                                                                       \
        const float* row_ = &pbuf[(r0 + (k)) * LW + c0];                       \
        float4 A_ = *reinterpret_cast<const float4*>(row_);                    \
        float4 B_ = *reinterpret_cast<const float4*>(row_ + 4);                \
        float s01 = A_.x + A_.y, s12 = A_.y + A_.z, s23 = A_.z + A_.w;         \
        float s34 = A_.w + B_.x, s45 = B_.x + B_.y, s56 = B_.y + B_.z;         \
        H1[slot][0] = s01 + s23 + B_.x;                                        \
        H1[slot][1] = s12 + s34 + B_.y;                                        \
        H1[slot][2] = s23 + s45 + B_.z;                                        \
        H1[slot][3] = s34 + s56 + B_.w;                                        \
        float q0 = A_.x * A_.x, q1 = A_.y * A_.y, q2 = A_.z * A_.z;            \
        float q3 = A_.w * A_.w, q4 = B_.x * B_.x, q5 = B_.y * B_.y;            \
        float q6 = B_.z * B_.z, q7 = B_.w * B_.w;                              \
        float t01 = q0 + q1, t12 = q1 + q2, t23 = q2 + q3;                     \
        float t34 = q3 + q4, t45 = q4 + q5, t56 = q5 + q6;                     \
        H2[slot][0] = t01 + t23 + q4;                                          \
        H2[slot][1] = t12 + t34 + q5;                                          \
        H2[slot][2] = t23 + t45 + q6;                                          \
        H2[slot][3] = t34 + t56 + q7;                                          \
        if ((stash) >= 0) pcst[(stash) < 0 ? 0 : (stash)] =                    \
            make_float4(A_.z, A_.w, B_.x, B_.y);                               \
    } while (0)

#define OUTROW(o)                                                              \
    do {                                                                       \
        float S1_[4], S2_[4];                                                  \
        _Pragma("unroll")                                                      \
        for (int c = 0; c < 4; ++c) {                                          \
            S1_[c] = ((H1[0][c] + H1[1][c]) + (H1[2][c] + H1[3][c])) + H1[4][c]; \
            S2_[c] = ((H2[0][c] + H2[1][c]) + (H2[2][c] + H2[3][c])) + H2[4][c]; \
        }                                                                      \
        const int gi_ = gibase + (o);                                          \
        const float cy_ = (float)(min(gi_, HALO) + min(IMG_H - 1 - gi_, HALO) + 1); \
        const float gv_[4] = {gt4[o].x, gt4[o].y, gt4[o].z, gt4[o].w};         \
        const float pv_[4] = {pcst[o].x, pcst[o].y, pcst[o].z, pcst[o].w};     \
        float wv_[4];                                                          \
        _Pragma("unroll")                                                      \
        for (int c = 0; c < 4; ++c) {                                          \
            float pc = pv_[c];                                                 \
            float C = cy_ * cxv[c];                                            \
            float acc = C * pc * pc - 2.0f * pc * S1_[c] + S2_[c];             \
            float cons = 1.0f - __fdividef(acc, C - 1.0f);                     \
            float ent = 1.0f + (pc * __logf(pc)                                \
                                + (1.0f - pc) * __logf(1.0f - pc)) * INV_LOG2; \
            float w = fmaxf(cons * ent, gv_[c]);                               \
            w = 0.9f * w + 0.1f;                                               \
            wv_[c] = w;                                                        \
            lsum += w;                                                         \
        }                                                                      \
        *reinterpret_cast<float4*>(&oimg[(size_t)gi_ * IMG_W + gj]) =          \
            make_float4(wv_[0], wv_[1], wv_[2], wv_[3]);                       \
    } while (0)

__global__ __launch_bounds__(256, 4) void wk_pass1(
    const float* __restrict__ y_d, const float* __restrict__ y_gt,
    float* __restrict__ out, float* __restrict__ sums)
{
    __shared__ float pbuf[LW * LW];   // 18.5 KB
    __shared__ float red[4];

    const int tiles_x = IMG_W / TILE;                    // 12
    const int tiles_per_img = tiles_x * (IMG_H / TILE);  // 144
    const int b = blockIdx.x;
    const int img = b / tiles_per_img;
    const int t = b - img * tiles_per_img;
    const int ti = t / tiles_x;
    const int tj = t - ti * tiles_x;
    const int gi0 = ti * TILE, gj0 = tj * TILE;

    const size_t img_off = (size_t)img * IMG_H * IMG_W;
    const float* __restrict__ yimg = y_d + img_off;
    const float* __restrict__ gimg = y_gt + img_off;
    float* __restrict__ oimg = out + img_off;

    const int tid = threadIdx.x;

    // ---- stage sigmoid(y): interior 68 rows x 64 cols, float4 loads ----
    // NOTE: OOB rows must stage p = 0.0 (NOT sigmoid(0) = 0.5) — the analytic
    // valid-count normalization (C-1) relies on OOB window entries being zero.
    for (int idx = tid; idx < 68 * 16; idx += 256) {
        int r = idx >> 4;
        int c4 = (idx & 15) << 2;
        int gi = gi0 - HALO + r;
        bool inb = (unsigned)gi < (unsigned)IMG_H;
        float4 v = make_float4(0.f, 0.f, 0.f, 0.f);
        if (inb)
            v = *reinterpret_cast<const float4*>(&yimg[(size_t)gi * IMG_W + gj0 + c4]);
        float* d = &pbuf[r * LW + HALO + c4];
        d[0] = inb ? fast_sigmoid(v.x) : 0.0f;
        d[1] = inb ? fast_sigmoid(v.y) : 0.0f;
        d[2] = inb ? fast_sigmoid(v.z) : 0.0f;
        d[3] = inb ? fast_sigmoid(v.w) : 0.0f;
    }
    // ---- halo cols: 68 rows x 4 cols (pbuf cols 0,1,66,67), guarded ----
    for (int idx = tid; idx < 68 * 4; idx += 256) {
        int r = idx >> 2;
        int h = idx & 3;
        int c  = (h < 2) ? h : (64 + h);             // 0,1,66,67
        int gj_ = gj0 - HALO + c;
        int gi = gi0 - HALO + r;
        float p = 0.f;
        if ((unsigned)gi < (unsigned)IMG_H && (unsigned)gj_ < (unsigned)IMG_W)
            p = fast_sigmoid(yimg[(size_t)gi * IMG_W + gj_]);
        pbuf[r * LW + c] = p;
    }
    __syncthreads();

    // ---- compute: each thread owns a 4x4 output block ----
    const int c0 = (tid & 15) << 2;   // tile col of first output (0..60)
    const int r0 = (tid >> 4) << 2;   // tile row of first output (0..60)
    const int gj = gj0 + c0;
    const int gibase = gi0 + r0;

    // preload gt rows early (latency hidden under stencil arithmetic)
    float4 gt4[4];
#pragma unroll
    for (int o = 0; o < 4; ++o)
        gt4[o] = *reinterpret_cast<const float4*>(&gimg[(size_t)(gibase + o) * IMG_W + gj]);

    float cxv[4];
#pragma unroll
    for (int c = 0; c < 4; ++c) {
        int g = gj + c;
        cxv[c] = (float)(min(g, HALO) + min(IMG_W - 1 - g, HALO) + 1);
    }

    float H1[5][4], H2[5][4];
    float4 pcst[4];
    float lsum = 0.0f;

    // ring fill: h-rows 0..4 (stash centers for out rows 0,1,2)
    LOAD_HROW(0, 0, -1);
    LOAD_HROW(1, 1, -1);
    LOAD_HROW(2, 2, 0);
    LOAD_HROW(3, 3, 1);
    LOAD_HROW(4, 4, 2);

    OUTROW(0);
    LOAD_HROW(5, 0, 3);   // slide; center row 5 feeds out row 3
    OUTROW(1);
    LOAD_HROW(6, 1, -1);
    OUTROW(2);
    LOAD_HROW(7, 2, -1);
    OUTROW(3);

    // ---- per-image sum: wave shfl-reduce -> LDS -> one atomic per block ----
#pragma unroll
    for (int off = 32; off > 0; off >>= 1)
        lsum += __shfl_down(lsum, off, 64);
    if ((tid & 63) == 0) red[tid >> 6] = lsum;
    __syncthreads();
    if (tid == 0)
        atomicAdd(&sums[img], (red[0] + red[1]) + (red[2] + red[3]));
}

// Pass 2: divide by per-image mean.
__global__ __launch_bounds__(256) void wk_pass2(
    float* __restrict__ out, const float* __restrict__ sums)
{
    const size_t total4 = (size_t)N_IMG * IMG_H * IMG_W / 4;
    const int per_img4 = IMG_H * IMG_W / 4;   // 147456
    for (size_t i = (size_t)blockIdx.x * blockDim.x + threadIdx.x; i < total4;
         i += (size_t)gridDim.x * blockDim.x) {
        int img = (int)(i / per_img4);
        float scale = (float)(IMG_H * IMG_W) / sums[img];
        float4 v = reinterpret_cast<float4*>(out)[i];
        v.x *= scale; v.y *= scale; v.z *= scale; v.w *= scale;
        reinterpret_cast<float4*>(out)[i] = v;
    }
}

extern "C" void kernel_launch(void* const* d_in, const int* in_sizes, int n_in,
                              void* d_out, int out_size, void* d_ws, size_t ws_size,
                              hipStream_t stream) {
    const float* y_d  = (const float*)d_in[0];
    const float* y_gt = (const float*)d_in[1];
    float* out  = (float*)d_out;
    float* sums = (float*)d_ws;

    hipMemsetAsync(sums, 0, N_IMG * sizeof(float), stream);

    const int tiles_per_img = (IMG_H / TILE) * (IMG_W / TILE);  // 144
    wk_pass1<<<dim3(N_IMG * tiles_per_img), dim3(256), 0, stream>>>(y_d, y_gt, out, sums);
    wk_pass2<<<dim3(2048), dim3(256), 0, stream>>>(out, sums);
}

// Round 6
// 105.697 us; speedup vs baseline: 2.3426x; 1.6915x over previous
//
#include <hip/hip_runtime.h>

#define IMG_H 768
#define IMG_W 768
#define N_IMG 32
#define TILE 64
#define HALO 2
#define LW 68              // 64 + 2*HALO
#define INV_LOG2 1.44269504088896340736f

__device__ __forceinline__ float fast_sigmoid(float y) {
    return 1.0f / (1.0f + __expf(-y));
}

__global__ __launch_bounds__(256) void wk_pass1(
    const float* __restrict__ y_d, const float* __restrict__ y_gt,
    float* __restrict__ out, float* __restrict__ sums)
{
    __shared__ float pbuf[LW * LW];   // 18.5 KB
    __shared__ float red[4];

    const int tiles_x = IMG_W / TILE;                    // 12
    const int tiles_per_img = tiles_x * (IMG_H / TILE);  // 144
    const int b = blockIdx.x;
    const int img = b / tiles_per_img;
    const int t = b - img * tiles_per_img;
    const int ti = t / tiles_x;
    const int tj = t - ti * tiles_x;
    const int gi0 = ti * TILE, gj0 = tj * TILE;

    const size_t img_off = (size_t)img * IMG_H * IMG_W;
    const float* __restrict__ yimg = y_d + img_off;
    const float* __restrict__ gimg = y_gt + img_off;
    float* __restrict__ oimg = out + img_off;

    const int tid = threadIdx.x;

    // ---- stage sigmoid(y): interior 68 rows x 64 cols, float4 loads ----
    // OOB pixels MUST stage p = 0.0 (not sigmoid(0)) — the analytic (C-1)
    // normalization relies on OOB window entries contributing zero.
    for (int idx = tid; idx < 68 * 16; idx += 256) {
        int r = idx >> 4;
        int c4 = (idx & 15) << 2;
        int gi = gi0 - HALO + r;
        bool inb = (unsigned)gi < (unsigned)IMG_H;
        float4 v = make_float4(0.f, 0.f, 0.f, 0.f);
        if (inb)
            v = *reinterpret_cast<const float4*>(&yimg[(size_t)gi * IMG_W + gj0 + c4]);
        float* d = &pbuf[r * LW + HALO + c4];
        d[0] = inb ? fast_sigmoid(v.x) : 0.0f;
        d[1] = inb ? fast_sigmoid(v.y) : 0.0f;
        d[2] = inb ? fast_sigmoid(v.z) : 0.0f;
        d[3] = inb ? fast_sigmoid(v.w) : 0.0f;
    }
    // ---- halo cols: 68 rows x 4 cols (pbuf cols 0,1,66,67), guarded ----
    for (int idx = tid; idx < 68 * 4; idx += 256) {
        int r = idx >> 2;
        int h = idx & 3;
        int c  = (h < 2) ? h : (64 + h);             // 0,1,66,67
        int gj_ = gj0 - HALO + c;
        int gi = gi0 - HALO + r;
        float p = 0.f;
        if ((unsigned)gi < (unsigned)IMG_H && (unsigned)gj_ < (unsigned)IMG_W)
            p = fast_sigmoid(yimg[(size_t)gi * IMG_W + gj_]);
        pbuf[r * LW + c] = p;
    }
    __syncthreads();

    // ---- compute: thread owns 4 cols x 4 rows (16x16 groups = 256 thr) ----
    // V1[cc]/V2[cc] = sum of p / p^2 over the current 5-row vertical window
    // for pbuf columns c0..c0+7 (covers the 4 outputs' 5-col spans).
    const int c0 = (tid & 15) << 2;    // tile col base 0..60
    const int rb = (tid >> 4) << 2;    // tile row base 0..60
    const int gj = gj0 + c0;

    float cxv[4];
#pragma unroll
    for (int c = 0; c < 4; ++c) {
        int g = gj + c;
        cxv[c] = (float)(min(g, HALO) + min(IMG_W - 1 - g, HALO) + 1);
    }

    float V1[8], V2[8];
#pragma unroll
    for (int cc = 0; cc < 8; ++cc) { V1[cc] = 0.f; V2[cc] = 0.f; }
#pragma unroll
    for (int k = 0; k < 5; ++k) {
        const float* row = &pbuf[(rb + k) * LW + c0];
        float4 A = *reinterpret_cast<const float4*>(row);
        float4 B = *reinterpret_cast<const float4*>(row + 4);
        float a[8] = {A.x, A.y, A.z, A.w, B.x, B.y, B.z, B.w};
#pragma unroll
        for (int cc = 0; cc < 8; ++cc) {
            V1[cc] += a[cc];
            V2[cc] = fmaf(a[cc], a[cc], V2[cc]);
        }
    }

    float lsum = 0.0f;

#pragma unroll
    for (int r = 0; r < 4; ++r) {
        const int gi = gi0 + rb + r;   // <= 767

        float4 g4 = *reinterpret_cast<const float4*>(&gimg[(size_t)gi * IMG_W + gj]);

        // center probabilities (pbuf row rb+r+2, cols c0+2..c0+5; 8B aligned)
        const float* crow = &pbuf[(rb + r + 2) * LW + (c0 + 2)];
        float2 pA = *reinterpret_cast<const float2*>(crow);
        float2 pB = *reinterpret_cast<const float2*>(crow + 2);
        float pcv[4] = {pA.x, pA.y, pB.x, pB.y};

        // horizontal 5-window sums over the vertical column sums
        float t01 = V1[0] + V1[1], t12 = V1[1] + V1[2], t23 = V1[2] + V1[3];
        float t34 = V1[3] + V1[4], t45 = V1[4] + V1[5], t56 = V1[5] + V1[6];
        float S1v[4] = { t01 + t23 + V1[4], t12 + t34 + V1[5],
                         t23 + t45 + V1[6], t34 + t56 + V1[7] };
        float u01 = V2[0] + V2[1], u12 = V2[1] + V2[2], u23 = V2[2] + V2[3];
        float u34 = V2[3] + V2[4], u45 = V2[4] + V2[5], u56 = V2[5] + V2[6];
        float S2v[4] = { u01 + u23 + V2[4], u12 + u34 + V2[5],
                         u23 + u45 + V2[6], u34 + u56 + V2[7] };

        float cy = (float)(min(gi, HALO) + min(IMG_H - 1 - gi, HALO) + 1);
        float gv[4] = {g4.x, g4.y, g4.z, g4.w};
        float wv[4];
#pragma unroll
        for (int c = 0; c < 4; ++c) {
            float pc = pcv[c];
            float C = cy * cxv[c];
            float acc = fmaf(C * pc, pc, fmaf(-2.0f * pc, S1v[c], S2v[c]));
            float cons = 1.0f - __fdividef(acc, C - 1.0f);
            float ent = fmaf(fmaf(pc, __logf(pc), (1.0f - pc) * __logf(1.0f - pc)),
                             INV_LOG2, 1.0f);
            float w = fmaxf(cons * ent, gv[c]);
            w = fmaf(w, 0.9f, 0.1f);
            wv[c] = w;
            lsum += w;
        }
        *reinterpret_cast<float4*>(&oimg[(size_t)gi * IMG_W + gj]) =
            make_float4(wv[0], wv[1], wv[2], wv[3]);

        if (r < 3) {   // slide: add pbuf row rb+r+5 (<=67), remove row rb+r
            const float* rin  = &pbuf[(rb + r + 5) * LW + c0];
            const float* rout = &pbuf[(rb + r) * LW + c0];
            float4 IA = *reinterpret_cast<const float4*>(rin);
            float4 IB = *reinterpret_cast<const float4*>(rin + 4);
            float4 OA = *reinterpret_cast<const float4*>(rout);
            float4 OB = *reinterpret_cast<const float4*>(rout + 4);
            float vin[8]  = {IA.x, IA.y, IA.z, IA.w, IB.x, IB.y, IB.z, IB.w};
            float vout[8] = {OA.x, OA.y, OA.z, OA.w, OB.x, OB.y, OB.z, OB.w};
#pragma unroll
            for (int cc = 0; cc < 8; ++cc) {
                V1[cc] += vin[cc] - vout[cc];
                V2[cc] += fmaf(vin[cc], vin[cc], -(vout[cc] * vout[cc]));
            }
        }
    }

    // ---- per-image sum: wave shfl-reduce -> LDS -> one atomic per block ----
#pragma unroll
    for (int off = 32; off > 0; off >>= 1)
        lsum += __shfl_down(lsum, off, 64);
    if ((tid & 63) == 0) red[tid >> 6] = lsum;
    __syncthreads();
    if (tid == 0)
        atomicAdd(&sums[img], (red[0] + red[1]) + (red[2] + red[3]));
}

// Pass 2: divide by per-image mean.
__global__ __launch_bounds__(256) void wk_pass2(
    float* __restrict__ out, const float* __restrict__ sums)
{
    const size_t total4 = (size_t)N_IMG * IMG_H * IMG_W / 4;
    const int per_img4 = IMG_H * IMG_W / 4;   // 147456
    for (size_t i = (size_t)blockIdx.x * blockDim.x + threadIdx.x; i < total4;
         i += (size_t)gridDim.x * blockDim.x) {
        int img = (int)(i / per_img4);
        float scale = (float)(IMG_H * IMG_W) / sums[img];
        float4 v = reinterpret_cast<float4*>(out)[i];
        v.x *= scale; v.y *= scale; v.z *= scale; v.w *= scale;
        reinterpret_cast<float4*>(out)[i] = v;
    }
}

extern "C" void kernel_launch(void* const* d_in, const int* in_sizes, int n_in,
                              void* d_out, int out_size, void* d_ws, size_t ws_size,
                              hipStream_t stream) {
    const float* y_d  = (const float*)d_in[0];
    const float* y_gt = (const float*)d_in[1];
    float* out  = (float*)d_out;
    float* sums = (float*)d_ws;

    hipMemsetAsync(sums, 0, N_IMG * sizeof(float), stream);

    const int tiles_per_img = (IMG_H / TILE) * (IMG_W / TILE);  // 144
    wk_pass1<<<dim3(N_IMG * tiles_per_img), dim3(256), 0, stream>>>(y_d, y_gt, out, sums);
    wk_pass2<<<dim3(2048), dim3(256), 0, stream>>>(out, sums);
}

// Round 7
// 103.740 us; speedup vs baseline: 2.3868x; 1.0189x over previous
//
#include <hip/hip_runtime.h>

#define IMG_H 768
#define IMG_W 768
#define N_IMG 32
#define TILE 64
#define HALO 2
#define LW 68              // 64 + 2*HALO
#define EW 68              // ebuf row stride (padded from 64; keeps 16B align)
#define INV_LOG2 1.44269504088896340736f

__device__ __forceinline__ float fast_sigmoid(float y) {
    return 1.0f / (1.0f + __expf(-y));
}

__global__ __launch_bounds__(256) void wk_pass1(
    const float* __restrict__ y_d, const float* __restrict__ y_gt,
    float* __restrict__ out, float* __restrict__ sums)
{
    __shared__ float pbuf[LW * LW];        // 18.5 KB: sigmoid probs + halo
    __shared__ float ebuf[TILE * EW];      // 17.4 KB: entropy, interior rows
    __shared__ float red[4];

    const int tiles_x = IMG_W / TILE;                    // 12
    const int tiles_per_img = tiles_x * (IMG_H / TILE);  // 144
    const int b = blockIdx.x;
    const int img = b / tiles_per_img;
    const int t = b - img * tiles_per_img;
    const int ti = t / tiles_x;
    const int tj = t - ti * tiles_x;
    const int gi0 = ti * TILE, gj0 = tj * TILE;

    const size_t img_off = (size_t)img * IMG_H * IMG_W;
    const float* __restrict__ yimg = y_d + img_off;
    const float* __restrict__ gimg = y_gt + img_off;
    float* __restrict__ oimg = out + img_off;

    const int tid = threadIdx.x;

    // ---- stage: p = sigmoid(y) into pbuf (68x68, OOB -> 0.0), and
    //      ent = 1 + (p*y - softplus(y))/ln2 into ebuf (interior 64 rows).
    //      softplus(y) = max(y,0) + log(1 + e^{-|y|}) shares exp with sigmoid:
    //      one exp + one log per pixel, zero logs in the stencil loop.
    for (int idx = tid; idx < 68 * 16; idx += 256) {
        int r = idx >> 4;
        int c4 = (idx & 15) << 2;
        int gi = gi0 - HALO + r;
        bool inb = (unsigned)gi < (unsigned)IMG_H;
        float4 v = make_float4(0.f, 0.f, 0.f, 0.f);
        if (inb)
            v = *reinterpret_cast<const float4*>(&yimg[(size_t)gi * IMG_W + gj0 + c4]);
        float yv[4] = {v.x, v.y, v.z, v.w};
        float pv[4], ev[4];
#pragma unroll
        for (int u = 0; u < 4; ++u) {
            float y  = yv[u];
            float E  = __expf(-fabsf(y));
            float tt = 1.0f + E;
            float rr = __fdividef(1.0f, tt);
            float p  = (y >= 0.0f) ? rr : E * rr;
            float l  = __logf(tt);                       // log(1+e^{-|y|})
            float sp = fmaxf(y, 0.0f) + l;
            pv[u] = inb ? p : 0.0f;                      // OOB MUST be 0.0
            ev[u] = fmaf(fmaf(p, y, -sp), INV_LOG2, 1.0f);
        }
        float* d = &pbuf[r * LW + HALO + c4];
        d[0] = pv[0]; d[1] = pv[1]; d[2] = pv[2]; d[3] = pv[3];
        if (r >= HALO && r < HALO + TILE) {              // interior row
            float* e = &ebuf[(r - HALO) * EW + c4];
            e[0] = ev[0]; e[1] = ev[1]; e[2] = ev[2]; e[3] = ev[3];
        }
    }
    // ---- halo cols: 68 rows x 4 cols (pbuf cols 0,1,66,67), p only ----
    for (int idx = tid; idx < 68 * 4; idx += 256) {
        int r = idx >> 2;
        int h = idx & 3;
        int c  = (h < 2) ? h : (64 + h);             // 0,1,66,67
        int gj_ = gj0 - HALO + c;
        int gi = gi0 - HALO + r;
        float p = 0.f;
        if ((unsigned)gi < (unsigned)IMG_H && (unsigned)gj_ < (unsigned)IMG_W)
            p = fast_sigmoid(yimg[(size_t)gi * IMG_W + gj_]);
        pbuf[r * LW + c] = p;
    }
    __syncthreads();

    // ---- compute: thread owns 4 cols x 4 rows (16x16 groups = 256 thr) ----
    const int c0 = (tid & 15) << 2;    // tile col base 0..60
    const int rb = (tid >> 4) << 2;    // tile row base 0..60
    const int gj = gj0 + c0;

    float cxv[4], rcp5[4];
#pragma unroll
    for (int c = 0; c < 4; ++c) {
        int g = gj + c;
        cxv[c] = (float)(min(g, HALO) + min(IMG_W - 1 - g, HALO) + 1);
        rcp5[c] = __fdividef(1.0f, fmaf(5.0f, cxv[c], -1.0f));  // interior cy=5
    }

    // V1/V2: vertical 5-row sums of p / p^2 for pbuf cols c0..c0+7.
    // keep[k]: the p-values of init rows rb+0..rb+2 (outgoing rows of the
    // 3 slides) retained in registers so slides only read the incoming row.
    float V1[8], V2[8], keep[3][8];
#pragma unroll
    for (int cc = 0; cc < 8; ++cc) { V1[cc] = 0.f; V2[cc] = 0.f; }
#pragma unroll
    for (int k = 0; k < 5; ++k) {
        const float* row = &pbuf[(rb + k) * LW + c0];
        float4 A = *reinterpret_cast<const float4*>(row);
        float4 B = *reinterpret_cast<const float4*>(row + 4);
        float a[8] = {A.x, A.y, A.z, A.w, B.x, B.y, B.z, B.w};
#pragma unroll
        for (int cc = 0; cc < 8; ++cc) {
            V1[cc] += a[cc];
            V2[cc] = fmaf(a[cc], a[cc], V2[cc]);
            if (k < 3) keep[k][cc] = a[cc];
        }
    }

    float lsum = 0.0f;

#pragma unroll
    for (int r = 0; r < 4; ++r) {
        const int gi = gi0 + rb + r;   // <= 767

        float4 g4 = *reinterpret_cast<const float4*>(&gimg[(size_t)gi * IMG_W + gj]);
        float4 e4 = *reinterpret_cast<const float4*>(&ebuf[(rb + r) * EW + c0]);

        // center probabilities (pbuf row rb+r+2, cols c0+2..c0+5; 8B aligned)
        const float* crow = &pbuf[(rb + r + 2) * LW + (c0 + 2)];
        float2 pA = *reinterpret_cast<const float2*>(crow);
        float2 pB = *reinterpret_cast<const float2*>(crow + 2);
        float pcv[4] = {pA.x, pA.y, pB.x, pB.y};

        // horizontal 5-window sums over the vertical column sums
        float t01 = V1[0] + V1[1], t12 = V1[1] + V1[2], t23 = V1[2] + V1[3];
        float t34 = V1[3] + V1[4], t45 = V1[4] + V1[5], t56 = V1[5] + V1[6];
        float S1v[4] = { t01 + t23 + V1[4], t12 + t34 + V1[5],
                         t23 + t45 + V1[6], t34 + t56 + V1[7] };
        float u01 = V2[0] + V2[1], u12 = V2[1] + V2[2], u23 = V2[2] + V2[3];
        float u34 = V2[3] + V2[4], u45 = V2[4] + V2[5], u56 = V2[5] + V2[6];
        float S2v[4] = { u01 + u23 + V2[4], u12 + u34 + V2[5],
                         u23 + u45 + V2[6], u34 + u56 + V2[7] };

        float cy = (float)(min(gi, HALO) + min(IMG_H - 1 - gi, HALO) + 1);
        float rc[4];
        if (cy == 5.0f) {
#pragma unroll
            for (int c = 0; c < 4; ++c) rc[c] = rcp5[c];
        } else {
#pragma unroll
            for (int c = 0; c < 4; ++c)
                rc[c] = __fdividef(1.0f, fmaf(cy, cxv[c], -1.0f));
        }

        float gv[4] = {g4.x, g4.y, g4.z, g4.w};
        float ev[4] = {e4.x, e4.y, e4.z, e4.w};
        float wv[4];
#pragma unroll
        for (int c = 0; c < 4; ++c) {
            float pc = pcv[c];
            float C = cy * cxv[c];
            float acc = fmaf(C * pc, pc, fmaf(-2.0f * pc, S1v[c], S2v[c]));
            float cons = fmaf(-acc, rc[c], 1.0f);
            float w = fmaxf(cons * ev[c], gv[c]);
            w = fmaf(w, 0.9f, 0.1f);
            wv[c] = w;
            lsum += w;
        }
        *reinterpret_cast<float4*>(&oimg[(size_t)gi * IMG_W + gj]) =
            make_float4(wv[0], wv[1], wv[2], wv[3]);

        if (r < 3) {   // slide: add incoming row rb+r+5; outgoing row from regs
            const float* rin = &pbuf[(rb + r + 5) * LW + c0];
            float4 IA = *reinterpret_cast<const float4*>(rin);
            float4 IB = *reinterpret_cast<const float4*>(rin + 4);
            float vin[8] = {IA.x, IA.y, IA.z, IA.w, IB.x, IB.y, IB.z, IB.w};
#pragma unroll
            for (int cc = 0; cc < 8; ++cc) {
                float vo = keep[r][cc];
                V1[cc] += vin[cc] - vo;
                V2[cc] += fmaf(vin[cc], vin[cc], -(vo * vo));
            }
        }
    }

    // ---- per-image sum: wave shfl-reduce -> LDS -> one atomic per block ----
#pragma unroll
    for (int off = 32; off > 0; off >>= 1)
        lsum += __shfl_down(lsum, off, 64);
    if ((tid & 63) == 0) red[tid >> 6] = lsum;
    __syncthreads();
    if (tid == 0)
        atomicAdd(&sums[img], (red[0] + red[1]) + (red[2] + red[3]));
}

// Pass 2: divide by per-image mean.
__global__ __launch_bounds__(256) void wk_pass2(
    float* __restrict__ out, const float* __restrict__ sums)
{
    const size_t total4 = (size_t)N_IMG * IMG_H * IMG_W / 4;
    const int per_img4 = IMG_H * IMG_W / 4;   // 147456
    for (size_t i = (size_t)blockIdx.x * blockDim.x + threadIdx.x; i < total4;
         i += (size_t)gridDim.x * blockDim.x) {
        int img = (int)(i / per_img4);
        float scale = (float)(IMG_H * IMG_W) / sums[img];
        float4 v = reinterpret_cast<float4*>(out)[i];
        v.x *= scale; v.y *= scale; v.z *= scale; v.w *= scale;
        reinterpret_cast<float4*>(out)[i] = v;
    }
}

extern "C" void kernel_launch(void* const* d_in, const int* in_sizes, int n_in,
                              void* d_out, int out_size, void* d_ws, size_t ws_size,
                              hipStream_t stream) {
    const float* y_d  = (const float*)d_in[0];
    const float* y_gt = (const float*)d_in[1];
    float* out  = (float*)d_out;
    float* sums = (float*)d_ws;

    hipMemsetAsync(sums, 0, N_IMG * sizeof(float), stream);

    const int tiles_per_img = (IMG_H / TILE) * (IMG_W / TILE);  // 144
    wk_pass1<<<dim3(N_IMG * tiles_per_img), dim3(256), 0, stream>>>(y_d, y_gt, out, sums);
    wk_pass2<<<dim3(2048), dim3(256), 0, stream>>>(out, sums);
}

// Round 8
// 101.600 us; speedup vs baseline: 2.4370x; 1.0211x over previous
//
#include <hip/hip_runtime.h>

#define IMG_H 768
#define IMG_W 768
#define N_IMG 32
#define TILE 64
#define HALO 2
#define LW 68              // 64 + 2*HALO
#define INV_LOG2 1.44269504088896340736f

__device__ __forceinline__ float fast_sigmoid(float y) {
    return 1.0f / (1.0f + __expf(-y));
}

__global__ __launch_bounds__(256) void wk_pass1(
    const float* __restrict__ y_d, const float* __restrict__ y_gt,
    float* __restrict__ out, float* __restrict__ sums)
{
    __shared__ float pbuf[LW * LW];   // 18.5 KB (only p lives in LDS now)
    __shared__ float red[4];

    const int tiles_x = IMG_W / TILE;                    // 12
    const int tiles_per_img = tiles_x * (IMG_H / TILE);  // 144
    const int b = blockIdx.x;
    const int img = b / tiles_per_img;
    const int t = b - img * tiles_per_img;
    const int ti = t / tiles_x;
    const int tj = t - ti * tiles_x;
    const int gi0 = ti * TILE, gj0 = tj * TILE;

    const size_t img_off = (size_t)img * IMG_H * IMG_W;
    const float* __restrict__ yimg = y_d + img_off;
    const float* __restrict__ gimg = y_gt + img_off;
    float* __restrict__ oimg = out + img_off;

    const int tid = threadIdx.x;
    const int c0 = (tid & 15) << 2;    // tile col base 0..60 (own block)
    const int rb = (tid >> 4) << 2;    // tile row base 0..60 (own block)
    const int gj = gj0 + c0;

    // ---- stage (a): own 4x4 block. Always in-bounds (tiles partition img).
    // p -> LDS (shared for stencil); ent + center p -> registers (private).
    // ent = 1 + (p*y - softplus(y))/ln2, softplus = max(y,0)+log(1+e^-|y|)
    // shares the exp with sigmoid: 1 exp + 1 log per pixel, none in the loop.
    float4 yv4[4];
#pragma unroll
    for (int r = 0; r < 4; ++r)
        yv4[r] = *reinterpret_cast<const float4*>(
            &yimg[(size_t)(gi0 + rb + r) * IMG_W + gj]);

    float4 pv4[4], ev4[4];
#pragma unroll
    for (int r = 0; r < 4; ++r) {
        float yy[4] = {yv4[r].x, yv4[r].y, yv4[r].z, yv4[r].w};
        float pp[4], ee[4];
#pragma unroll
        for (int u = 0; u < 4; ++u) {
            float y  = yy[u];
            float E  = __expf(-fabsf(y));
            float tt = 1.0f + E;
            float rr = __fdividef(1.0f, tt);
            float p  = (y >= 0.0f) ? rr : E * rr;
            float sp = fmaxf(y, 0.0f) + __logf(tt);
            pp[u] = p;
            ee[u] = fmaf(fmaf(p, y, -sp), INV_LOG2, 1.0f);
        }
        pv4[r] = make_float4(pp[0], pp[1], pp[2], pp[3]);
        ev4[r] = make_float4(ee[0], ee[1], ee[2], ee[3]);
        *reinterpret_cast<float4*>(&pbuf[(rb + HALO + r) * LW + (c0 + HALO)]) =
            pv4[r];
    }

    // ---- stage (b): halo, p only. Rows {0,1,66,67} x all 68 cols (272) +
    // cols {0,1,66,67} x rows 2..65 (256) = 528 items. OOB -> p = 0.0
    // (the analytic C-1 normalization relies on OOB entries being zero).
    for (int idx = tid; idx < 528; idx += 256) {
        int pr, pc;
        if (idx < 272) {
            int rsel = idx / 68;
            pr = (rsel < 2) ? rsel : (64 + rsel);    // 0,1,66,67
            pc = idx - rsel * 68;
        } else {
            int k = idx - 272;
            pr = (k >> 2) + 2;                       // 2..65
            int h = k & 3;
            pc = (h < 2) ? h : (64 + h);             // 0,1,66,67
        }
        int gi_ = gi0 - HALO + pr;
        int gj_ = gj0 - HALO + pc;
        float p = 0.f;
        if ((unsigned)gi_ < (unsigned)IMG_H && (unsigned)gj_ < (unsigned)IMG_W)
            p = fast_sigmoid(yimg[(size_t)gi_ * IMG_W + gj_]);
        pbuf[pr * LW + pc] = p;
    }
    __syncthreads();

    // ---- compute: vertical sliding 5-row window over pbuf cols c0..c0+7 ----
    float cxv[4], rcp5[4];
#pragma unroll
    for (int c = 0; c < 4; ++c) {
        int g = gj + c;
        cxv[c] = (float)(min(g, HALO) + min(IMG_W - 1 - g, HALO) + 1);
        rcp5[c] = __fdividef(1.0f, fmaf(5.0f, cxv[c], -1.0f));  // interior cy=5
    }

    float V1[8], V2[8];
#pragma unroll
    for (int cc = 0; cc < 8; ++cc) { V1[cc] = 0.f; V2[cc] = 0.f; }
#pragma unroll
    for (int k = 0; k < 5; ++k) {
        const float* row = &pbuf[(rb + k) * LW + c0];
        float4 A = *reinterpret_cast<const float4*>(row);
        float4 B = *reinterpret_cast<const float4*>(row + 4);
        float a[8] = {A.x, A.y, A.z, A.w, B.x, B.y, B.z, B.w};
#pragma unroll
        for (int cc = 0; cc < 8; ++cc) {
            V1[cc] += a[cc];
            V2[cc] = fmaf(a[cc], a[cc], V2[cc]);
        }
    }

    float lsum = 0.0f;

#pragma unroll
    for (int r = 0; r < 4; ++r) {
        const int gi = gi0 + rb + r;   // <= 767

        float4 g4 = *reinterpret_cast<const float4*>(&gimg[(size_t)gi * IMG_W + gj]);

        // horizontal 5-window sums over the vertical column sums
        float t01 = V1[0] + V1[1], t12 = V1[1] + V1[2], t23 = V1[2] + V1[3];
        float t34 = V1[3] + V1[4], t45 = V1[4] + V1[5], t56 = V1[5] + V1[6];
        float S1v[4] = { t01 + t23 + V1[4], t12 + t34 + V1[5],
                         t23 + t45 + V1[6], t34 + t56 + V1[7] };
        float u01 = V2[0] + V2[1], u12 = V2[1] + V2[2], u23 = V2[2] + V2[3];
        float u34 = V2[3] + V2[4], u45 = V2[4] + V2[5], u56 = V2[5] + V2[6];
        float S2v[4] = { u01 + u23 + V2[4], u12 + u34 + V2[5],
                         u23 + u45 + V2[6], u34 + u56 + V2[7] };

        float cy = (float)(min(gi, HALO) + min(IMG_H - 1 - gi, HALO) + 1);
        float rc[4];
        if (cy == 5.0f) {
#pragma unroll
            for (int c = 0; c < 4; ++c) rc[c] = rcp5[c];
        } else {
#pragma unroll
            for (int c = 0; c < 4; ++c)
                rc[c] = __fdividef(1.0f, fmaf(cy, cxv[c], -1.0f));
        }

        float pcv[4] = {pv4[r].x, pv4[r].y, pv4[r].z, pv4[r].w};
        float ev[4]  = {ev4[r].x, ev4[r].y, ev4[r].z, ev4[r].w};
        float gv[4]  = {g4.x, g4.y, g4.z, g4.w};
        float wv[4];
#pragma unroll
        for (int c = 0; c < 4; ++c) {
            float pc = pcv[c];
            float C = cy * cxv[c];
            float acc = fmaf(C * pc, pc, fmaf(-2.0f * pc, S1v[c], S2v[c]));
            float cons = fmaf(-acc, rc[c], 1.0f);
            float w = fmaxf(cons * ev[c], gv[c]);
            w = fmaf(w, 0.9f, 0.1f);
            wv[c] = w;
            lsum += w;
        }
        *reinterpret_cast<float4*>(&oimg[(size_t)gi * IMG_W + gj]) =
            make_float4(wv[0], wv[1], wv[2], wv[3]);

        if (r < 3) {   // slide: add incoming row rb+r+5, remove row rb+r (LDS)
            const float* rin  = &pbuf[(rb + r + 5) * LW + c0];
            const float* rout = &pbuf[(rb + r) * LW + c0];
            float4 IA = *reinterpret_cast<const float4*>(rin);
            float4 IB = *reinterpret_cast<const float4*>(rin + 4);
            float4 OA = *reinterpret_cast<const float4*>(rout);
            float4 OB = *reinterpret_cast<const float4*>(rout + 4);
            float vin[8]  = {IA.x, IA.y, IA.z, IA.w, IB.x, IB.y, IB.z, IB.w};
            float vout[8] = {OA.x, OA.y, OA.z, OA.w, OB.x, OB.y, OB.z, OB.w};
#pragma unroll
            for (int cc = 0; cc < 8; ++cc) {
                V1[cc] += vin[cc] - vout[cc];
                V2[cc] += fmaf(vin[cc], vin[cc], -(vout[cc] * vout[cc]));
            }
        }
    }

    // ---- per-image sum: wave shfl-reduce -> LDS -> one atomic per block ----
#pragma unroll
    for (int off = 32; off > 0; off >>= 1)
        lsum += __shfl_down(lsum, off, 64);
    if ((tid & 63) == 0) red[tid >> 6] = lsum;
    __syncthreads();
    if (tid == 0)
        atomicAdd(&sums[img], (red[0] + red[1]) + (red[2] + red[3]));
}

// Pass 2: divide by per-image mean.
__global__ __launch_bounds__(256) void wk_pass2(
    float* __restrict__ out, const float* __restrict__ sums)
{
    const size_t total4 = (size_t)N_IMG * IMG_H * IMG_W / 4;
    const int per_img4 = IMG_H * IMG_W / 4;   // 147456
    for (size_t i = (size_t)blockIdx.x * blockDim.x + threadIdx.x; i < total4;
         i += (size_t)gridDim.x * blockDim.x) {
        int img = (int)(i / per_img4);
        float scale = (float)(IMG_H * IMG_W) / sums[img];
        float4 v = reinterpret_cast<float4*>(out)[i];
        v.x *= scale; v.y *= scale; v.z *= scale; v.w *= scale;
        reinterpret_cast<float4*>(out)[i] = v;
    }
}

extern "C" void kernel_launch(void* const* d_in, const int* in_sizes, int n_in,
                              void* d_out, int out_size, void* d_ws, size_t ws_size,
                              hipStream_t stream) {
    const float* y_d  = (const float*)d_in[0];
    const float* y_gt = (const float*)d_in[1];
    float* out  = (float*)d_out;
    float* sums = (float*)d_ws;

    hipMemsetAsync(sums, 0, N_IMG * sizeof(float), stream);

    const int tiles_per_img = (IMG_H / TILE) * (IMG_W / TILE);  // 144
    wk_pass1<<<dim3(N_IMG * tiles_per_img), dim3(256), 0, stream>>>(y_d, y_gt, out, sums);
    wk_pass2<<<dim3(2048), dim3(256), 0, stream>>>(out, sums);
}